// Round 2
// baseline (527.901 us; speedup 1.0000x reference)
//
#include <hip/hip_runtime.h>
#include <hip/hip_bf16.h>

#define NB 64
#define NP 8732
#define NO 32
#define NC 81
#define NROWS (NB * NP)

// ws layout (total 16,404 bytes — deliberately tiny; round-1 NaN was likely
// an OOB write from a 4.5 MB layout exceeding ws_size):
//   [0,     16384) : u64 bestPrior[NB*NO]   packed (iou_bits<<32)|~p
//   [16384, 16400) : float accum[4]         {cross, l1, iou, npos}
//   [16400, 16404) : int   flag             1 = inputs are f32, 0 = bf16

__device__ __forceinline__ float b2f(__hip_bfloat16 x) { return __bfloat162float(x); }

__device__ __forceinline__ float ldf(const void* p, int isf32, size_t i) {
    return isf32 ? ((const float*)p)[i]
                 : __bfloat162float(((const __hip_bfloat16*)p)[i]);
}

// Zero bestPrior/accum; detect input dtype from prior_bboxes. If the buffer is
// really f32, reading it as bf16 makes the low-half "elements" random 16-bit
// patterns (~50% have |v|>8 or NaN); true bf16 priors are all <= ~1.3.
__global__ void init_kernel(const void* __restrict__ prior,
                            unsigned long long* __restrict__ bestPrior,
                            float* __restrict__ accum, int* __restrict__ flag) {
    int i = threadIdx.x;
    for (int j = i; j < NB * NO; j += blockDim.x) bestPrior[j] = 0ull;
    if (i < 4) accum[i] = 0.0f;
    if (i == 0) {
        const __hip_bfloat16* pb = (const __hip_bfloat16*)prior;
        int cnt = 0;
        for (int k = 0; k < 128; ++k) {
            float v = b2f(pb[k]);
            if (!(fabsf(v) <= 8.0f)) cnt++;   // catches NaN too
        }
        *flag = (cnt >= 8) ? 1 : 0;
    }
}

// Per (b,o): argmax over priors -> packed u64 atomicMax. Ties -> smallest p
// (float max + ballot + ffs gives first-occurrence, matching jnp.argmax axis=0).
__global__ __launch_bounds__(256) void match_kernel(
        const void* __restrict__ prior,            // [P,4] cxcywh
        const void* __restrict__ tb,               // [B,O,4] xywh
        unsigned long long* __restrict__ bestPrior,// [B,O]
        const int* __restrict__ flag) {
    const int isf32 = *flag;
    const int b = blockIdx.y;
    const int p = blockIdx.x * 256 + threadIdx.x;
    const int lane = threadIdx.x & 63;
    const int p_base = p - lane;

    __shared__ float tx0[NO], ty0[NO], tx1[NO], ty1[NO], ta[NO];
    if (threadIdx.x < NO) {
        int o = threadIdx.x;
        size_t base = ((size_t)(b * NO + o)) * 4;
        float x = ldf(tb, isf32, base),     y = ldf(tb, isf32, base + 1);
        float w = ldf(tb, isf32, base + 2), h = ldf(tb, isf32, base + 3);
        tx0[o] = x; ty0[o] = y; tx1[o] = x + w; ty1[o] = y + h; ta[o] = w * h;
    }
    __syncthreads();

    const bool valid = (p < NP);
    float px0 = 0.f, py0 = 0.f, px1 = 0.f, py1 = 0.f, pa = 0.f;
    if (valid) {
        size_t base = (size_t)p * 4;
        float cx = ldf(prior, isf32, base),     cy = ldf(prior, isf32, base + 1);
        float w  = ldf(prior, isf32, base + 2), h  = ldf(prior, isf32, base + 3);
        px0 = cx - w * 0.5f; py0 = cy - h * 0.5f;
        px1 = cx + w * 0.5f; py1 = cy + h * 0.5f;
        pa = (px1 - px0) * (py1 - py0);
    }

    for (int o = 0; o < NO; ++o) {
        float lbx = fmaxf(px0, tx0[o]), lby = fmaxf(py0, ty0[o]);
        float ubx = fminf(px1, tx1[o]), uby = fminf(py1, ty1[o]);
        float w = fmaxf(ubx - lbx, 0.0f), h = fmaxf(uby - lby, 0.0f);
        float inter = w * h;
        float iou = valid ? (inter / (pa + ta[o] - inter + 1e-6f)) : -1.0f;
        float mx = iou;
        for (int s = 1; s < 64; s <<= 1) mx = fmaxf(mx, __shfl_xor(mx, s));
        unsigned long long ball = __ballot(iou == mx);
        if (lane == 0 && mx >= 0.0f) {
            int wl = __ffsll(ball) - 1;          // lowest lane = smallest p
            unsigned wp = (unsigned)(p_base + wl);
            unsigned long long packed =
                (((unsigned long long)__float_as_uint(mx)) << 32) | (~wp);
            atomicMax(&bestPrior[b * NO + o], packed);
        }
    }
}

// One wave per row: recompute per-row best object (lanes 0..31 = objects),
// apply force-match from bestPrior, then log-softmax CE + box losses.
__global__ __launch_bounds__(256) void loss_kernel(
        const void* __restrict__ plocs,   // [B,P,4] cxcywh predictions
        const void* __restrict__ pcls,    // [B,P,C] logits
        const void* __restrict__ prior,   // [P,4] cxcywh
        const void* __restrict__ tb,      // [B,O,4] xywh
        const int* __restrict__ tlab,     // [B,O]
        const unsigned long long* __restrict__ bestPrior,
        const int* __restrict__ flag,
        float* __restrict__ accum) {
    const int isf32 = *flag;
    const int lane = threadIdx.x & 63;
    const int wid = threadIdx.x >> 6;
    const int o = lane & 31;              // lanes 32..63 duplicate 0..31
    const int stride = gridDim.x * 4;

    float c_sum = 0.f, l1_sum = 0.f, iou_sum = 0.f, np_sum = 0.f;

    for (int row = blockIdx.x * 4 + wid; row < NROWS; row += stride) {
        const int b = row / NP;
        const int p = row - b * NP;

        // prior box p (wave-uniform broadcast loads)
        size_t pb = (size_t)p * 4;
        float cx = ldf(prior, isf32, pb),     cy = ldf(prior, isf32, pb + 1);
        float pw = ldf(prior, isf32, pb + 2), ph = ldf(prior, isf32, pb + 3);
        float px0 = cx - pw * 0.5f, py0 = cy - ph * 0.5f;
        float px1 = cx + pw * 0.5f, py1 = cy + ph * 0.5f;
        float pa = (px1 - px0) * (py1 - py0);

        // target box o (L1/L2-cached, 256B per batch image)
        size_t tbase = ((size_t)(b * NO + o)) * 4;
        float tx = ldf(tb, isf32, tbase),     ty = ldf(tb, isf32, tbase + 1);
        float tw = ldf(tb, isf32, tbase + 2), th = ldf(tb, isf32, tbase + 3);
        float tX0 = tx, tY0 = ty, tX1 = tx + tw, tY1 = ty + th;

        float lbx = fmaxf(px0, tX0), lby = fmaxf(py0, tY0);
        float ubx = fminf(px1, tX1), uby = fminf(py1, tY1);
        float w = fmaxf(ubx - lbx, 0.f), h = fmaxf(uby - lby, 0.f);
        float inter = w * h;
        float iou = inter / (pa + tw * th - inter + 1e-6f);

        float mx = iou;
        for (int s = 1; s < 64; s <<= 1) mx = fmaxf(mx, __shfl_xor(mx, s));
        unsigned b32 = (unsigned)__ballot(iou == mx);   // low 32 = lanes 0..31
        int bo = __ffs(b32) - 1;                         // first-occurrence argmax
        float biou = mx;

        // force-match: does this prior win some object? (last o wins on dup)
        unsigned forced_p = ~(unsigned)(bestPrior[b * NO + o] & 0xffffffffull);
        unsigned f32m = (unsigned)__ballot(forced_p == (unsigned)p);
        if (f32m) { bo = 31 - __clz(f32m); biou = 1.0f; }

        int lab = tlab[b * NO + bo];
        if (biou < 0.5f) lab = 0;

        // log-softmax over 81 classes, lanes hold c=lane and c=lane+64
        const size_t rbase = (size_t)row * NC;
        float v0 = ldf(pcls, isf32, rbase + lane);
        float v1 = (lane < NC - 64) ? ldf(pcls, isf32, rbase + 64 + lane) : -1e30f;
        float m = fmaxf(v0, v1);
        for (int s = 1; s < 64; s <<= 1) m = fmaxf(m, __shfl_xor(m, s));
        float e = __expf(v0 - m) + ((lane < NC - 64) ? __expf(v1 - m) : 0.0f);
        for (int s = 1; s < 64; s <<= 1) e += __shfl_xor(e, s);
        float lse = m + __logf(e);
        float xl = (lab < 64) ? __shfl(v0, lab) : __shfl(v1, lab - 64);

        if (lane == 0) {
            c_sum += (lse - xl);
            if (lab != 0) {
                np_sum += 1.0f;
                size_t mb = ((size_t)(b * NO + bo)) * 4;
                float mtx = ldf(tb, isf32, mb),     mty = ldf(tb, isf32, mb + 1);
                float mtw = ldf(tb, isf32, mb + 2), mth = ldf(tb, isf32, mb + 3);
                float mX0 = mtx, mY0 = mty, mX1 = mtx + mtw, mY1 = mty + mth;
                float tcx = (mX0 + mX1) * 0.5f, tcy = (mY0 + mY1) * 0.5f;
                size_t lbase = (size_t)row * 4;
                float qcx = ldf(plocs, isf32, lbase),     qcy = ldf(plocs, isf32, lbase + 1);
                float qw  = ldf(plocs, isf32, lbase + 2), qh  = ldf(plocs, isf32, lbase + 3);
                l1_sum += fabsf(qcx - tcx) + fabsf(qcy - tcy)
                        + fabsf(qw - mtw) + fabsf(qh - mth);
                float qX0 = qcx - qw * 0.5f, qY0 = qcy - qh * 0.5f;
                float qX1 = qcx + qw * 0.5f, qY1 = qcy + qh * 0.5f;
                float ilbx = fmaxf(mX0, qX0), ilby = fmaxf(mY0, qY0);
                float iubx = fminf(mX1, qX1), iuby = fminf(mY1, qY1);
                float iw = fmaxf(iubx - ilbx, 0.f), ih = fmaxf(iuby - ilby, 0.f);
                float iinter = iw * ih;
                float areaq = (qX1 - qX0) * (qY1 - qY0);
                float areat = (mX1 - mX0) * (mY1 - mY0);
                iou_sum += 1.0f - iinter / (areat + areaq - iinter + 1e-6f);
            }
        }
    }

    __shared__ float sh[4][4];
    if (lane == 0) { sh[wid][0] = c_sum; sh[wid][1] = l1_sum;
                     sh[wid][2] = iou_sum; sh[wid][3] = np_sum; }
    __syncthreads();
    if (threadIdx.x == 0) {
        float a0 = 0, a1 = 0, a2 = 0, a3 = 0;
        for (int k = 0; k < 4; ++k) { a0 += sh[k][0]; a1 += sh[k][1];
                                      a2 += sh[k][2]; a3 += sh[k][3]; }
        atomicAdd(&accum[0], a0);
        atomicAdd(&accum[1], a1);
        atomicAdd(&accum[2], a2);
        atomicAdd(&accum[3], a3);
    }
}

__global__ void finalize_kernel(const float* __restrict__ accum,
                                const int* __restrict__ flag, void* __restrict__ out) {
    if (threadIdx.x == 0) {
        float cross = accum[0] / (float)NROWS;
        float npos = accum[3];
        float loc = accum[1] / (npos * 4.0f);
        float iou = accum[2] / npos;
        if (*flag) {
            float* o = (float*)out;
            o[0] = loc; o[1] = cross; o[2] = iou;
        } else {
            __hip_bfloat16* o = (__hip_bfloat16*)out;
            o[0] = __float2bfloat16(loc);
            o[1] = __float2bfloat16(cross);
            o[2] = __float2bfloat16(iou);
        }
    }
}

extern "C" void kernel_launch(void* const* d_in, const int* in_sizes, int n_in,
                              void* d_out, int out_size, void* d_ws, size_t ws_size,
                              hipStream_t stream) {
    const void* plocs = d_in[0];            // [B,P,4]
    const void* pcls  = d_in[1];            // [B,P,C]
    const void* prior = d_in[2];            // [P,4]
    const void* tb    = d_in[3];            // [B,O,4]
    const int*  tlab  = (const int*)d_in[4];// [B,O]

    char* w = (char*)d_ws;
    unsigned long long* bestPrior = (unsigned long long*)w;      // 16384 B
    float* accum = (float*)(w + 16384);                          // 16 B
    int*   flag  = (int*)(w + 16400);                            // 4 B

    hipLaunchKernelGGL(init_kernel, dim3(1), dim3(256), 0, stream,
                       prior, bestPrior, accum, flag);

    dim3 gA((NP + 255) / 256, NB);
    hipLaunchKernelGGL(match_kernel, gA, dim3(256), 0, stream,
                       prior, tb, bestPrior, flag);

    hipLaunchKernelGGL(loss_kernel, dim3(2048), dim3(256), 0, stream,
                       plocs, pcls, prior, tb, tlab, bestPrior, flag, accum);

    hipLaunchKernelGGL(finalize_kernel, dim3(1), dim3(64), 0, stream,
                       accum, flag, d_out);
}

// Round 6
// 493.105 us; speedup vs baseline: 1.0706x; 1.0706x over previous
//
#include <hip/hip_runtime.h>
#include <hip/hip_bf16.h>

#define NB 64
#define NP 8732
#define NO 32
#define NC 81
#define NROWS (NB * NP)

// ws layout (16,404 B): [0,16384) u64 bestPrior[NB*NO] packed (iou_bits<<32)|~p
//                       [16384,16400) float accum[4] {cross, l1, iou, npos}
//                       [16400,16404) int flag (1 = f32 inputs, 0 = bf16)
// R1 kernels (init/match/finalize + all loss constructs) are verbatim from the
// round that PASSED with absmax 0.0. Only change: loss loop is 4-row ILP.

__device__ __forceinline__ float b2f(__hip_bfloat16 x) { return __bfloat162float(x); }

__device__ __forceinline__ float ldf(const void* p, int isf32, size_t i) {
    return isf32 ? ((const float*)p)[i]
                 : __bfloat162float(((const __hip_bfloat16*)p)[i]);
}

__global__ void init_kernel(const void* __restrict__ prior,
                            unsigned long long* __restrict__ bestPrior,
                            float* __restrict__ accum, int* __restrict__ flag) {
    int i = threadIdx.x;
    for (int j = i; j < NB * NO; j += blockDim.x) bestPrior[j] = 0ull;
    if (i < 4) accum[i] = 0.0f;
    if (i == 0) {
        const __hip_bfloat16* pb = (const __hip_bfloat16*)prior;
        int cnt = 0;
        for (int k = 0; k < 128; ++k) {
            float v = b2f(pb[k]);
            if (!(fabsf(v) <= 8.0f)) cnt++;
        }
        *flag = (cnt >= 8) ? 1 : 0;
    }
}

__global__ __launch_bounds__(256) void match_kernel(
        const void* __restrict__ prior,            // [P,4] cxcywh
        const void* __restrict__ tb,               // [B,O,4] xywh
        unsigned long long* __restrict__ bestPrior,// [B,O]
        const int* __restrict__ flag) {
    const int isf32 = *flag;
    const int b = blockIdx.y;
    const int p = blockIdx.x * 256 + threadIdx.x;
    const int lane = threadIdx.x & 63;
    const int p_base = p - lane;

    __shared__ float tx0[NO], ty0[NO], tx1[NO], ty1[NO], ta[NO];
    if (threadIdx.x < NO) {
        int o = threadIdx.x;
        size_t base = ((size_t)(b * NO + o)) * 4;
        float x = ldf(tb, isf32, base),     y = ldf(tb, isf32, base + 1);
        float w = ldf(tb, isf32, base + 2), h = ldf(tb, isf32, base + 3);
        tx0[o] = x; ty0[o] = y; tx1[o] = x + w; ty1[o] = y + h; ta[o] = w * h;
    }
    __syncthreads();

    const bool valid = (p < NP);
    float px0 = 0.f, py0 = 0.f, px1 = 0.f, py1 = 0.f, pa = 0.f;
    if (valid) {
        size_t base = (size_t)p * 4;
        float cx = ldf(prior, isf32, base),     cy = ldf(prior, isf32, base + 1);
        float w  = ldf(prior, isf32, base + 2), h  = ldf(prior, isf32, base + 3);
        px0 = cx - w * 0.5f; py0 = cy - h * 0.5f;
        px1 = cx + w * 0.5f; py1 = cy + h * 0.5f;
        pa = (px1 - px0) * (py1 - py0);
    }

    for (int o = 0; o < NO; ++o) {
        float lbx = fmaxf(px0, tx0[o]), lby = fmaxf(py0, ty0[o]);
        float ubx = fminf(px1, tx1[o]), uby = fminf(py1, ty1[o]);
        float w = fmaxf(ubx - lbx, 0.0f), h = fmaxf(uby - lby, 0.0f);
        float inter = w * h;
        float iou = valid ? (inter / (pa + ta[o] - inter + 1e-6f)) : -1.0f;
        float mx = iou;
        for (int s = 1; s < 64; s <<= 1) mx = fmaxf(mx, __shfl_xor(mx, s));
        unsigned long long ball = __ballot(iou == mx);
        if (lane == 0 && mx >= 0.0f) {
            int wl = __ffsll((long long)ball) - 1;   // lowest lane = smallest p
            unsigned wp = (unsigned)(p_base + wl);
            unsigned long long packed =
                (((unsigned long long)__float_as_uint(mx)) << 32) | (~wp);
            atomicMax(&bestPrior[b * NO + o], packed);
        }
    }
}

// R1 wave-per-row loss, 4-row ILP. All constructs identical to the passing
// version; act[] is wave-uniform so shuffles/ballots stay uniform.
__global__ __launch_bounds__(256) void loss_kernel(
        const void* __restrict__ plocs,   // [B,P,4] cxcywh predictions
        const void* __restrict__ pcls,    // [B,P,C] logits
        const void* __restrict__ prior,   // [P,4] cxcywh
        const void* __restrict__ tb,      // [B,O,4] xywh
        const int* __restrict__ tlab,     // [B,O]
        const unsigned long long* __restrict__ bestPrior,
        const int* __restrict__ flag,
        float* __restrict__ accum) {
    const int isf32 = *flag;
    const int lane = threadIdx.x & 63;
    const int wid = threadIdx.x >> 6;
    const int o = lane & 31;
    const int stride = gridDim.x * 4;

    float c_sum = 0.f, l1_sum = 0.f, iou_sum = 0.f, np_sum = 0.f;

    for (int r0 = blockIdx.x * 4 + wid; r0 < NROWS; r0 += 4 * stride) {
        int rows[4], bq[4], pq[4];
        bool act[4];
        #pragma unroll
        for (int k = 0; k < 4; ++k) {
            int r = r0 + k * stride;
            act[k] = (r < NROWS);
            rows[k] = act[k] ? r : (NROWS - 1);
            bq[k] = rows[k] / NP;
            pq[k] = rows[k] - bq[k] * NP;
        }

        float iou[4];
        #pragma unroll
        for (int k = 0; k < 4; ++k) {
            size_t pb = (size_t)pq[k] * 4;
            float cx = ldf(prior, isf32, pb),     cy = ldf(prior, isf32, pb + 1);
            float pw = ldf(prior, isf32, pb + 2), ph = ldf(prior, isf32, pb + 3);
            float px0 = cx - pw * 0.5f, py0 = cy - ph * 0.5f;
            float px1 = cx + pw * 0.5f, py1 = cy + ph * 0.5f;
            float pa = (px1 - px0) * (py1 - py0);
            size_t tbase = ((size_t)(bq[k] * NO + o)) * 4;
            float tx = ldf(tb, isf32, tbase),     ty = ldf(tb, isf32, tbase + 1);
            float tw = ldf(tb, isf32, tbase + 2), th = ldf(tb, isf32, tbase + 3);
            float lbx = fmaxf(px0, tx),      lby = fmaxf(py0, ty);
            float ubx = fminf(px1, tx + tw), uby = fminf(py1, ty + th);
            float w = fmaxf(ubx - lbx, 0.f), h = fmaxf(uby - lby, 0.f);
            float inter = w * h;
            iou[k] = inter / (pa + tw * th - inter + 1e-6f);
        }

        float mx[4] = {iou[0], iou[1], iou[2], iou[3]};
        for (int s = 1; s < 64; s <<= 1) {
            #pragma unroll
            for (int k = 0; k < 4; ++k) mx[k] = fmaxf(mx[k], __shfl_xor(mx[k], s));
        }

        int bo[4]; float biou[4];
        #pragma unroll
        for (int k = 0; k < 4; ++k) {
            unsigned b32 = (unsigned)__ballot(iou[k] == mx[k]);
            bo[k] = __ffs(b32) - 1;                  // first-occurrence argmax
            biou[k] = mx[k];
            unsigned forced_p = ~(unsigned)(bestPrior[bq[k] * NO + o] & 0xffffffffull);
            unsigned fm = (unsigned)__ballot(forced_p == (unsigned)pq[k]);
            if (fm) { bo[k] = 31 - __clz(fm); biou[k] = 1.0f; }
        }

        int lab[4];
        #pragma unroll
        for (int k = 0; k < 4; ++k) {
            lab[k] = tlab[bq[k] * NO + bo[k]];
            if (biou[k] < 0.5f) lab[k] = 0;
        }

        float v0[4], v1[4];
        #pragma unroll
        for (int k = 0; k < 4; ++k) {
            size_t rbase = (size_t)rows[k] * NC;
            v0[k] = ldf(pcls, isf32, rbase + lane);
            v1[k] = (lane < NC - 64) ? ldf(pcls, isf32, rbase + 64 + lane) : -1e30f;
        }

        float m[4];
        #pragma unroll
        for (int k = 0; k < 4; ++k) m[k] = fmaxf(v0[k], v1[k]);
        for (int s = 1; s < 64; s <<= 1) {
            #pragma unroll
            for (int k = 0; k < 4; ++k) m[k] = fmaxf(m[k], __shfl_xor(m[k], s));
        }
        float e[4];
        #pragma unroll
        for (int k = 0; k < 4; ++k)
            e[k] = __expf(v0[k] - m[k]) + ((lane < NC - 64) ? __expf(v1[k] - m[k]) : 0.0f);
        for (int s = 1; s < 64; s <<= 1) {
            #pragma unroll
            for (int k = 0; k < 4; ++k) e[k] += __shfl_xor(e[k], s);
        }

        #pragma unroll
        for (int k = 0; k < 4; ++k) {
            float lse = m[k] + __logf(e[k]);
            float xl = (lab[k] < 64) ? __shfl(v0[k], lab[k]) : __shfl(v1[k], lab[k] - 64);
            if (lane == 0 && act[k]) {
                c_sum += (lse - xl);
                if (lab[k] != 0) {
                    np_sum += 1.0f;
                    size_t mb = ((size_t)(bq[k] * NO + bo[k])) * 4;
                    float mtx = ldf(tb, isf32, mb),     mty = ldf(tb, isf32, mb + 1);
                    float mtw = ldf(tb, isf32, mb + 2), mth = ldf(tb, isf32, mb + 3);
                    float mX0 = mtx, mY0 = mty, mX1 = mtx + mtw, mY1 = mty + mth;
                    float tcx = (mX0 + mX1) * 0.5f, tcy = (mY0 + mY1) * 0.5f;
                    size_t lbase = (size_t)rows[k] * 4;
                    float qcx = ldf(plocs, isf32, lbase),     qcy = ldf(plocs, isf32, lbase + 1);
                    float qw  = ldf(plocs, isf32, lbase + 2), qh  = ldf(plocs, isf32, lbase + 3);
                    l1_sum += fabsf(qcx - tcx) + fabsf(qcy - tcy)
                            + fabsf(qw - mtw) + fabsf(qh - mth);
                    float qX0 = qcx - qw * 0.5f, qY0 = qcy - qh * 0.5f;
                    float qX1 = qcx + qw * 0.5f, qY1 = qcy + qh * 0.5f;
                    float ilbx = fmaxf(mX0, qX0), ilby = fmaxf(mY0, qY0);
                    float iubx = fminf(mX1, qX1), iuby = fminf(mY1, qY1);
                    float iw = fmaxf(iubx - ilbx, 0.f), ih = fmaxf(iuby - ilby, 0.f);
                    float iinter = iw * ih;
                    float areaq = (qX1 - qX0) * (qY1 - qY0);
                    float areat = (mX1 - mX0) * (mY1 - mY0);
                    iou_sum += 1.0f - iinter / (areat + areaq - iinter + 1e-6f);
                }
            }
        }
    }

    __shared__ float sh[4][4];
    if (lane == 0) { sh[wid][0] = c_sum; sh[wid][1] = l1_sum;
                     sh[wid][2] = iou_sum; sh[wid][3] = np_sum; }
    __syncthreads();
    if (threadIdx.x == 0) {
        float a0 = 0, a1 = 0, a2 = 0, a3 = 0;
        for (int k = 0; k < 4; ++k) { a0 += sh[k][0]; a1 += sh[k][1];
                                      a2 += sh[k][2]; a3 += sh[k][3]; }
        atomicAdd(&accum[0], a0);
        atomicAdd(&accum[1], a1);
        atomicAdd(&accum[2], a2);
        atomicAdd(&accum[3], a3);
    }
}

__global__ void finalize_kernel(const float* __restrict__ accum,
                                const int* __restrict__ flag, void* __restrict__ out) {
    if (threadIdx.x == 0) {
        float cross = accum[0] / (float)NROWS;
        float npos = accum[3];
        float loc = accum[1] / (npos * 4.0f);
        float iou = accum[2] / npos;
        if (*flag) {
            float* o = (float*)out;
            o[0] = loc; o[1] = cross; o[2] = iou;
        } else {
            __hip_bfloat16* o = (__hip_bfloat16*)out;
            o[0] = __float2bfloat16(loc);
            o[1] = __float2bfloat16(cross);
            o[2] = __float2bfloat16(iou);
        }
    }
}

extern "C" void kernel_launch(void* const* d_in, const int* in_sizes, int n_in,
                              void* d_out, int out_size, void* d_ws, size_t ws_size,
                              hipStream_t stream) {
    const void* plocs = d_in[0];            // [B,P,4]
    const void* pcls  = d_in[1];            // [B,P,C]
    const void* prior = d_in[2];            // [P,4]
    const void* tb    = d_in[3];            // [B,O,4]
    const int*  tlab  = (const int*)d_in[4];// [B,O]

    char* w = (char*)d_ws;
    unsigned long long* bestPrior = (unsigned long long*)w;      // 16384 B
    float* accum = (float*)(w + 16384);                          // 16 B
    int*   flag  = (int*)(w + 16400);                            // 4 B

    hipLaunchKernelGGL(init_kernel, dim3(1), dim3(256), 0, stream,
                       prior, bestPrior, accum, flag);

    dim3 gA((NP + 255) / 256, NB);
    hipLaunchKernelGGL(match_kernel, gA, dim3(256), 0, stream,
                       prior, tb, bestPrior, flag);

    hipLaunchKernelGGL(loss_kernel, dim3(2048), dim3(256), 0, stream,
                       plocs, pcls, prior, tb, tlab, bestPrior, flag, accum);

    hipLaunchKernelGGL(finalize_kernel, dim3(1), dim3(64), 0, stream,
                       accum, flag, d_out);
}